// Round 13
// baseline (88.438 us; speedup 1.0000x reference)
//
#include <hip/hip_runtime.h>

// CRF loss: A=8, S=200, B=64, T=32. scores (A,S,B,T,T) f32, targets (A,S,B) i32,
// mask (S,B) bool, a_mask (A,B) bool -- bool width (u8 vs i32) runtime-detected.
// R13: TWO chains per 8-wave block (chains 2c,2c+1: same a, adjacent b).
// Per phase: each producer wave loads+exps ONE 4KB tile (4 steps x 2 chains)
// into the double-buffered LDS ring; waves 0,1 consume chain 0,1 IN PARALLEL
// (4 serial steps each). Sync/pipeline skeleton verbatim R12 (PASSED 80.5us):
// named A/B register sets with 2-phase cover, raw lgkm-only barrier, runtime
// consumer j-loop, renorm at s%4==0.
constexpr int A_ = 8, S_ = 200, B_ = 64, T_ = 32;
constexpr int START_TAG = 30, END_TAG = 31;
constexpr int NW = 8;                      // waves per block
constexpr int JP = 4;                      // steps per chain per phase
#define LOG2E 1.44269504088896340736f
#define LN2   0.69314718055994530942f

#if __has_builtin(__builtin_amdgcn_exp2f)
#define EXP2F(x) __builtin_amdgcn_exp2f(x)
#else
#define EXP2F(x) __expf((x) * LN2)
#endif

__device__ __forceinline__ int load_flag(const void* p, bool u8, int idx) {
    return u8 ? (int)((const unsigned char*)p)[idx] : ((const int*)p)[idx];
}

// LDS-writes-visible barrier WITHOUT vmcnt drain (proven R7/R12).
#define LGKM_BARRIER do {                                                \
        asm volatile("s_waitcnt lgkmcnt(0)" ::: "memory");               \
        __builtin_amdgcn_s_barrier();                                    \
        asm volatile("" ::: "memory");                                   \
    } while (0)

__global__ __launch_bounds__(NW * 64)
void crf_loss_kernel(const float* __restrict__ scores,
                     const int* __restrict__ targets,
                     const void* __restrict__ mask,
                     const void* __restrict__ amask,
                     float* __restrict__ out)
{
    const int c = blockIdx.x;              // 0..255
    const int chain0 = 2 * c;              // chains (2c, 2c+1); a = chain>>6 same
    const int a = chain0 >> 6;
    const int b0 = chain0 & (B_ - 1);      // chain1 has b0+1
    const int tid = threadIdx.x;
    const int wv = tid >> 6;               // 0..7
    const int lane = tid & 63;
    const int t = lane & 31;
    const int fbase = (lane >> 5) << 4;    // 0 or 16

    // bool width detect: mask row 0 is all-true. int view: 1 -> int32, 0x01010101 -> uint8
    const bool bool_u8 = (((const int*)mask)[0] != 1);
    const int act0 = load_flag(amask, bool_u8, chain0);
    const int act1 = load_flag(amask, bool_u8, chain0 + 1);
    if (!act0 && !act1) return;            // both chains masked (~4% of blocks)

    __shared__ __align__(16) float ebuf[2][2][JP][T_ * T_];  // half x chain x j: 64KB
    __shared__ float gside[2][2][JP];                        // raw gold-path scores
    __shared__ int tg_lds[2][S_];
    __shared__ float wlds[2][T_];                            // per-chain w vector

    // ---- first-false mask index per chain (prefix mask) ----
    int L0 = S_, L1 = S_;
    for (int base = 0; base < S_; base += 64) {
        int i = base + lane;
        int mv0 = (i < S_) ? load_flag(mask, bool_u8, i * B_ + b0) : 1;
        unsigned long long bal0 = __ballot(mv0 == 0);
        if (bal0 != 0ull && L0 == S_) L0 = base + (int)__builtin_ctzll(bal0);
        int mv1 = (i < S_) ? load_flag(mask, bool_u8, i * B_ + b0 + 1) : 1;
        unsigned long long bal1 = __ballot(mv1 == 0);
        if (bal1 != 0ull && L1 == S_) L1 = base + (int)__builtin_ctzll(bal1);
    }
    if (!act0) L0 = 1;                     // masked chain: no loads, no consume
    if (!act1) L1 = 1;

    for (int i = tid; i < S_; i += NW * 64) {
        tg_lds[0][i] = targets[((size_t)a * S_ + i) * B_ + b0];
        tg_lds[1][i] = targets[((size_t)a * S_ + i) * B_ + b0 + 1];
    }
    __syncthreads();                        // tg_lds ready (prologue drain OK)

    const size_t s_stride = (size_t)B_ * T_ * T_;            // 65536 floats per step
    const float* cb0 = scores + ((size_t)a * S_ * B_ + b0) * (T_ * T_);
    const float* cb1 = cb0 + T_ * T_;      // b0+1

    // producer assignment: wave wv handles chain (wv>>2), step-slot (wv&3)
    const int mych = wv >> 2;
    const int myj = wv & 3;
    const float* mycb = mych ? cb1 : cb0;
    const int myL = mych ? L1 : L0;

    // consumer state (waves 0,1 only; wlds is private to its consumer wave)
    float wcur = 0.0f, C2 = 0.0f, tg = 0.0f;
    if (wv == 0 && act0) {
        wcur = EXP2F(cb0[START_TAG * T_ + t] * LOG2E);
        if (lane < 32) wlds[0][lane] = wcur;
        tg = cb0[tg_lds[0][0]];
    }
    if (wv == 1 && act1) {
        wcur = EXP2F(cb1[START_TAG * T_ + t] * LOG2E);
        if (lane < 32) wlds[1][lane] = wcur;
        tg = cb1[tg_lds[1][0]];
    }

    const int Lmax = (L0 > L1) ? L0 : L1;
    const int nch = (Lmax - 1 + JP - 1) / JP;   // phases (block-uniform)

#define E4(DST, SRC) do {                                                \
        DST.x = EXP2F(SRC.x * LOG2E); DST.y = EXP2F(SRC.y * LOG2E);      \
        DST.z = EXP2F(SRC.z * LOG2E); DST.w = EXP2F(SRC.w * LOG2E);      \
    } while (0)

#define RENORM(CH) do {                                                  \
        float m_ = wcur;                                                 \
        m_ = fmaxf(m_, __shfl_xor(m_, 1));                               \
        m_ = fmaxf(m_, __shfl_xor(m_, 2));                               \
        m_ = fmaxf(m_, __shfl_xor(m_, 4));                               \
        m_ = fmaxf(m_, __shfl_xor(m_, 8));                               \
        m_ = fmaxf(m_, __shfl_xor(m_, 16));                              \
        int eb_ = (__float_as_int(m_) >> 23) & 0xff;                     \
        C2 += (float)(eb_ - 127);                                        \
        float sc2_ = __int_as_float((254 - eb_) << 23);                  \
        wcur *= sc2_;                                                    \
        if (lane < 32) wlds[CH][lane] = wcur;                            \
    } while (0)

#define TLOAD(Q0, Q1, Q2, Q3, GR, SC) do {                               \
        const int s_ = (SC);                                             \
        if (s_ < myL) {                                                  \
            const float*  p_  = mycb + (size_t)s_ * s_stride;            \
            const float4* p4_ = (const float4*)p_;                       \
            Q0 = p4_[lane];       Q1 = p4_[64 + lane];                   \
            Q2 = p4_[128 + lane]; Q3 = p4_[192 + lane];                  \
            GR = p_[tg_lds[mych][s_]];                                   \
        }                                                                \
    } while (0)

    // consumer phase for chain CH: runtime j-loop (proven form, verbatim R12)
#define CONSUME(CH, KK) do {                                             \
        const int kb_ = (KK) & 1;                                        \
        const int Lc_ = (CH) ? L1 : L0;                                  \
        const int jmax_ = min(JP, Lc_ - 1 - (KK) * JP);                  \
        for (int j = 0; j < jmax_; ++j) {                                \
            const int s = 1 + (KK) * JP + j;                             \
            const float* eb = &ebuf[kb_][CH][j][0];                      \
            float4 wa_ = *(const float4*)&wlds[CH][fbase];               \
            float4 wb_ = *(const float4*)&wlds[CH][fbase + 4];           \
            float4 wc_ = *(const float4*)&wlds[CH][fbase + 8];           \
            float4 wd_ = *(const float4*)&wlds[CH][fbase + 12];          \
            float e_[16];                                                \
            _Pragma("unroll")                                            \
            for (int i = 0; i < 16; ++i)                                 \
                e_[i] = eb[((fbase + i) << 5) | t];                      \
            float s0_ = fmaf(e_[3], wa_.w, fmaf(e_[2], wa_.z,            \
                        fmaf(e_[1], wa_.y, e_[0] * wa_.x)));             \
            float s1_ = fmaf(e_[7], wb_.w, fmaf(e_[6], wb_.z,            \
                        fmaf(e_[5], wb_.y, e_[4] * wb_.x)));             \
            float s2_ = fmaf(e_[11], wc_.w, fmaf(e_[10], wc_.z,          \
                        fmaf(e_[9], wc_.y, e_[8] * wc_.x)));             \
            float s3_ = fmaf(e_[15], wd_.w, fmaf(e_[14], wd_.z,          \
                        fmaf(e_[13], wd_.y, e_[12] * wd_.x)));           \
            float s_ = (s0_ + s1_) + (s2_ + s3_);                        \
            s_ += __shfl_xor(s_, 32);                                    \
            wcur = s_;                                                   \
            if (lane < 32) wlds[CH][lane] = s_;                          \
            tg += gside[kb_][CH][j];                                     \
            if ((s & 3) == 0) RENORM(CH);                                \
        }                                                                \
    } while (0)

    // One phase with named buffer set: exp-write my tile of chunk KK, refill
    // the SAME regs with chunk KK+2 (first read 2 phases later), raw barrier,
    // consumer waves run their 4 steps. No register rotation (proven R12).
#define PHASE(Q0, Q1, Q2, Q3, GQ, KK) do {                               \
        const int k_ = (KK);                                             \
        const int scur_ = 1 + k_ * JP + myj;                             \
        if (scur_ < myL) {                                               \
            float4* ebw = (float4*)&ebuf[k_ & 1][mych][myj][0];          \
            float4 e0, e1, e2, e3;                                       \
            E4(e0, Q0); E4(e1, Q1); E4(e2, Q2); E4(e3, Q3);              \
            ebw[lane] = e0; ebw[64 + lane] = e1;                         \
            ebw[128 + lane] = e2; ebw[192 + lane] = e3;                  \
            if (lane == 0) gside[k_ & 1][mych][myj] = GQ;                \
        }                                                                \
        TLOAD(Q0, Q1, Q2, Q3, GQ, scur_ + 2 * JP);                       \
        LGKM_BARRIER;                                                    \
        if (wv == 0) { if (act0) CONSUME(0, k_); }                       \
        else if (wv == 1) { if (act1) CONSUME(1, k_); }                  \
    } while (0)

    // ---- prologue prefetch: chunk 0 -> A, chunk 1 -> B ----
    float4 a0, a1, a2, a3, b0r, b1r, b2r, b3r;
    float ga = 0.0f, gb = 0.0f;
    TLOAD(a0, a1, a2, a3, ga, 1 + myj);
    TLOAD(b0r, b1r, b2r, b3r, gb, 1 + JP + myj);

    for (int k = 0; k < nch; k += 2) {
        PHASE(a0, a1, a2, a3, ga, k);
        if (k + 1 < nch)
            PHASE(b0r, b1r, b2r, b3r, gb, k + 1);
    }

    // ---- epilogue: per-chain logZ and loss ----
    if (wv == 0 && act0) {
        float wend = __shfl(wcur, END_TAG);
        float logZ = __logf(wend) + C2 * LN2;
        if (lane == 0)
            atomicAdd(out, (logZ - tg) * (1.0f / (float)B_));
    }
    if (wv == 1 && act1) {
        float wend = __shfl(wcur, END_TAG);
        float logZ = __logf(wend) + C2 * LN2;
        if (lane == 0)
            atomicAdd(out, (logZ - tg) * (1.0f / (float)B_));
    }
}

extern "C" void kernel_launch(void* const* d_in, const int* in_sizes, int n_in,
                              void* d_out, int out_size, void* d_ws, size_t ws_size,
                              hipStream_t stream) {
    const float* scores = (const float*)d_in[0];
    const int* targets  = (const int*)d_in[1];
    const void* mask    = d_in[2];
    const void* amask   = d_in[3];
    float* out = (float*)d_out;

    hipMemsetAsync(out, 0, sizeof(float), stream);
    crf_loss_kernel<<<dim3(A_ * B_ / 2), dim3(NW * 64), 0, stream>>>(
        scores, targets, mask, amask, out);
}